// Round 2
// baseline (243.903 us; speedup 1.0000x reference)
//
#include <hip/hip_runtime.h>
#include <stdint.h>

// MultiHeadAttentionLayer: bf16-MFMA pipeline, f32 output.
//   prep_weights: Wq/Wk/Wv ([H,D,E] f32) -> W^T bf16 [H*E][D]; Wo -> Wo^T bf16
//   proj_gemm:    q,k = [B,H,S,E] bf16; v stored transposed [B,H,E,S] bf16
//   attn_kernel:  flash-style online softmax, threshold+upper-tri mask
//   out_gemm:     att[4096x1024] @ Wo^T + bo -> d_out (f32)

typedef __attribute__((ext_vector_type(8))) short bf16x8;
typedef __attribute__((ext_vector_type(4))) float f32x4;

#define DEVFN static __device__ __forceinline__

static constexpr int S_ = 2048;
static constexpr int H_ = 16;

DEVFN unsigned short f2bf(float x) {
  union { float f; uint32_t u; } v; v.f = x;
  const uint32_t r = v.u + 0x7fffu + ((v.u >> 16) & 1u);  // RNE
  return (unsigned short)(r >> 16);
}

DEVFN f32x4 fzero() { f32x4 v = {0.f, 0.f, 0.f, 0.f}; return v; }

// global -> LDS direct copy, 16B per lane; LDS dest must be wave-uniform base.
DEVFN void gld_lds16(const void* g, void* lds) {
  __builtin_amdgcn_global_load_lds(
      (const __attribute__((address_space(1))) void*)g,
      (__attribute__((address_space(3))) void*)lds, 16, 0, 0);
}

// ---------------------------------------------------------------------------
// Weight prep: dst[c][d] = W[h=c>>6][d][e=c&63] (z<3) or Wo[d][c] (z==3), bf16
// ---------------------------------------------------------------------------
__global__ void prep_weights(const float* __restrict__ Wq, const float* __restrict__ Wk,
                             const float* __restrict__ Wv, const float* __restrict__ Wo,
                             unsigned short* __restrict__ dstBase) {
  const int z = blockIdx.z;
  const float* src = (z == 0) ? Wq : (z == 1) ? Wk : (z == 2) ? Wv : Wo;
  unsigned short* dst = dstBase + (size_t)z * (1024u * 1024u);
  const int idx = blockIdx.x * 256 + threadIdx.x;  // 131072 threads
  const int c = idx & 1023;
  const int d0 = (idx >> 10) << 3;
  unsigned short hv[8];
#pragma unroll
  for (int t = 0; t < 8; ++t) {
    const int d = d0 + t;
    const float v = (z < 3) ? src[(size_t)((c >> 6) * 1024 + d) * 64 + (c & 63)]
                            : src[(size_t)d * 1024 + c];
    hv[t] = f2bf(v);
  }
  *(uint4*)(dst + (size_t)c * 1024 + d0) = *(const uint4*)hv;
}

// ---------------------------------------------------------------------------
// QKV projection GEMM: C[4096x1024] = A(f32) * W^T(bf16), 128x128 tile, BK=32.
// LDS tiles are [128 rows][32 bf16]; 16B chunks XOR-swizzled by ((row>>1)&3).
// ---------------------------------------------------------------------------
__global__ __launch_bounds__(256, 2)
void proj_gemm(const float* __restrict__ Qm, const float* __restrict__ Tm,
               const float* __restrict__ Vm, const unsigned short* __restrict__ Wt,
               const float* __restrict__ bq, const float* __restrict__ bk,
               const float* __restrict__ bv, unsigned short* __restrict__ qb,
               unsigned short* __restrict__ kb, unsigned short* __restrict__ vtb) {
  __shared__ unsigned short At[128 * 32];
  __shared__ unsigned short Bt[128 * 32];

  const int tid = threadIdx.x;
  const int lane = tid & 63;
  const int w = tid >> 6;
  const int g = lane >> 4, c = lane & 15;
  const int wm = w >> 1, wn = w & 1;

  const int m0 = blockIdx.x * 128;
  const int proj = blockIdx.y >> 3;
  const int n0 = (blockIdx.y & 7) * 128;

  const float* Asrc = (proj == 0) ? Qm : (proj == 1) ? Tm : Vm;
  const unsigned short* W = Wt + (size_t)proj * (1024u * 1024u);

  f32x4 acc[4][4];
#pragma unroll
  for (int i = 0; i < 4; ++i)
#pragma unroll
    for (int j = 0; j < 4; ++j) acc[i][j] = fzero();

  const int ar = tid >> 1;  // A row 0..127
  const int ah = tid & 1;   // which 16-f32 half of the 32-wide k slice

  for (int kt = 0; kt < 32; ++kt) {
    const int k0 = kt * 32;
    // --- stage A: f32 -> bf16, swizzled ds_write_b128 ---
    {
      const float* s = Asrc + (size_t)(m0 + ar) * 1024 + k0 + ah * 16;
      const float4 f0 = ((const float4*)s)[0];
      const float4 f1 = ((const float4*)s)[1];
      const float4 f2 = ((const float4*)s)[2];
      const float4 f3 = ((const float4*)s)[3];
      unsigned short hv[16];
      hv[0] = f2bf(f0.x); hv[1] = f2bf(f0.y); hv[2] = f2bf(f0.z); hv[3] = f2bf(f0.w);
      hv[4] = f2bf(f1.x); hv[5] = f2bf(f1.y); hv[6] = f2bf(f1.z); hv[7] = f2bf(f1.w);
      hv[8] = f2bf(f2.x); hv[9] = f2bf(f2.y); hv[10] = f2bf(f2.z); hv[11] = f2bf(f2.w);
      hv[12] = f2bf(f3.x); hv[13] = f2bf(f3.y); hv[14] = f2bf(f3.z); hv[15] = f2bf(f3.w);
      const int swz = (ar >> 1) & 3;
      *(uint4*)&At[ar * 32 + ((ah * 2 + 0) ^ swz) * 8] = *(const uint4*)&hv[0];
      *(uint4*)&At[ar * 32 + ((ah * 2 + 1) ^ swz) * 8] = *(const uint4*)&hv[8];
    }
    // --- stage B via global_load_lds (linear LDS dest, pre-swizzled source) ---
#pragma unroll
    for (int u = 0; u < 2; ++u) {
      const int row = w * 32 + u * 16 + (lane >> 2);
      const int ch = (lane & 3) ^ ((row >> 1) & 3);
      gld_lds16(W + (size_t)(n0 + row) * 1024 + k0 + ch * 8,
                &Bt[(w * 32 + u * 16) * 32]);
    }
    __syncthreads();

    bf16x8 af[4], bfr[4];
#pragma unroll
    for (int mi = 0; mi < 4; ++mi) {
      const int row = wm * 64 + mi * 16 + c;
      af[mi] = *(const bf16x8*)&At[row * 32 + ((g ^ ((row >> 1) & 3))) * 8];
    }
#pragma unroll
    for (int ni = 0; ni < 4; ++ni) {
      const int row = wn * 64 + ni * 16 + c;
      bfr[ni] = *(const bf16x8*)&Bt[row * 32 + ((g ^ ((row >> 1) & 3))) * 8];
    }
#pragma unroll
    for (int mi = 0; mi < 4; ++mi)
#pragma unroll
      for (int ni = 0; ni < 4; ++ni)
        acc[mi][ni] = __builtin_amdgcn_mfma_f32_16x16x32_bf16(af[mi], bfr[ni],
                                                              acc[mi][ni], 0, 0, 0);
    __syncthreads();
  }

  const float* bias = (proj == 0) ? bq : (proj == 1) ? bk : bv;
#pragma unroll
  for (int ni = 0; ni < 4; ++ni) {
    const int colb = n0 + wn * 64 + ni * 16 + c;  // 0..1023 = h*64+e
    const float bc = bias[colb];
    const int hh = colb >> 6, e = colb & 63;
#pragma unroll
    for (int mi = 0; mi < 4; ++mi) {
#pragma unroll
      for (int r = 0; r < 4; ++r) {
        const int row = m0 + wm * 64 + mi * 16 + g * 4 + r;  // b*S+s
        const int bb = row >> 11, s = row & 2047;
        const float val = acc[mi][ni][r] + bc;
        if (proj < 2) {
          unsigned short* d = (proj == 0) ? qb : kb;
          d[(((size_t)(bb * H_ + hh)) * S_ + s) * 64 + e] = f2bf(val);
        } else {  // v stored transposed per head: [B,H,E,S]
          vtb[(((size_t)(bb * H_ + hh)) * 64 + e) * S_ + s] = f2bf(val);
        }
      }
    }
  }
}

// ---------------------------------------------------------------------------
// Flash attention. Block: 4 waves x 32 q-rows. KV tile = 32.
// K tile [32][64] bf16 (8 chunks/row, swz row&7), rows permuted sigma(r)
//   (evens then odds) so P frag cols (n=0,1) are j-adjacent.
// V^T tile [64][32] bf16 (4 chunks/row, swz (e>>1)&3).
// P: per-wave LDS [32 rows][40 shorts] (80B rows, 16B-aligned b128 reads).
// ---------------------------------------------------------------------------
__global__ __launch_bounds__(256, 2)
void attn_kernel(const unsigned short* __restrict__ qb,
                 const unsigned short* __restrict__ kb,
                 const unsigned short* __restrict__ vtb,
                 unsigned short* __restrict__ att) {
  __shared__ unsigned short Kt[32 * 64];
  __shared__ unsigned short Vt[64 * 32];
  __shared__ unsigned short Pt[4][32 * 40];

  const int tid = threadIdx.x;
  const int lane = tid & 63;
  const int w = tid >> 6;
  const int g = lane >> 4, c = lane & 15;
  const int bz = blockIdx.z, hh = blockIdx.y;
  const int q0 = blockIdx.x * 128 + w * 32;
  const size_t bh = (size_t)(bz * H_ + hh);
  const unsigned short* qh = qb + bh * S_ * 64;
  const unsigned short* kh = kb + bh * S_ * 64;
  const unsigned short* vh = vtb + bh * (size_t)64 * S_;

  // Q fragments held in registers for the whole block row.
  bf16x8 aq[2][2];
#pragma unroll
  for (int m = 0; m < 2; ++m)
#pragma unroll
    for (int t = 0; t < 2; ++t)
      aq[m][t] = *(const bf16x8*)&qh[(size_t)(q0 + m * 16 + c) * 64 + t * 32 + g * 8];

  f32x4 O[2][4];
#pragma unroll
  for (int m = 0; m < 2; ++m)
#pragma unroll
    for (int n = 0; n < 4; ++n) O[m][n] = fzero();
  float mrow[2][4], lrow[2][4];
#pragma unroll
  for (int m = 0; m < 2; ++m)
#pragma unroll
    for (int r = 0; r < 4; ++r) { mrow[m][r] = -1e30f; lrow[m][r] = 0.f; }

  constexpr float L2E = 1.4426950408889634f;

  for (int jt = 0; jt < 64; ++jt) {
    const int j0 = jt * 32;
    {  // stage K: LDS row holds global k-row j0 + sigma(row)
      const int row = w * 8 + (lane >> 3);
      const int sig = (row < 16) ? (2 * row) : (2 * row - 31);
      const int ch = (lane & 7) ^ (row & 7);
      gld_lds16(kh + (size_t)(j0 + sig) * 64 + ch * 8, &Kt[(w * 8) * 64]);
    }
    {  // stage V^T
      const int e = w * 16 + (lane >> 2);
      const int ch = (lane & 3) ^ ((e >> 1) & 3);
      gld_lds16(vh + (size_t)e * S_ + j0 + ch * 8, &Vt[(w * 16) * 32]);
    }
    __syncthreads();

    // QK^T: S[32q x 32j], frag col c of n-frag corresponds to j = 2c+n.
    f32x4 sa[2][2];
#pragma unroll
    for (int m = 0; m < 2; ++m)
#pragma unroll
      for (int n = 0; n < 2; ++n) sa[m][n] = fzero();
#pragma unroll
    for (int n = 0; n < 2; ++n) {
      const int row = n * 16 + c;
      const int swz = row & 7;
#pragma unroll
      for (int t = 0; t < 2; ++t) {
        const bf16x8 bk8 = *(const bf16x8*)&Kt[row * 64 + ((t * 4 + g) ^ swz) * 8];
#pragma unroll
        for (int m = 0; m < 2; ++m)
          sa[m][n] = __builtin_amdgcn_mfma_f32_16x16x32_bf16(aq[m][t], bk8,
                                                             sa[m][n], 0, 0, 0);
      }
    }

    // mask + online softmax; rows live in 16-lane groups (C layout).
#pragma unroll
    for (int m = 0; m < 2; ++m) {
#pragma unroll
      for (int r = 0; r < 4; ++r) {
        const int iq = q0 + m * 16 + g * 4 + r;
        float v0 = sa[m][0][r];
        float v1 = sa[m][1][r];
        v0 = (v0 > 0.1f) ? v0 : 0.f;
        v1 = (v1 > 0.1f) ? v1 : 0.f;
        const int jc = j0 + 2 * c;
        if (jc > iq) v0 += 1.f;
        if (jc + 1 > iq) v1 += 1.f;
        v0 *= 0.125f;  // 1/sqrt(64)
        v1 *= 0.125f;
        float mx = fmaxf(v0, v1);
        mx = fmaxf(mx, __shfl_xor(mx, 1));
        mx = fmaxf(mx, __shfl_xor(mx, 2));
        mx = fmaxf(mx, __shfl_xor(mx, 4));
        mx = fmaxf(mx, __shfl_xor(mx, 8));
        const float mnew = fmaxf(mrow[m][r], mx);
        const float alpha = __builtin_amdgcn_exp2f((mrow[m][r] - mnew) * L2E);
        mrow[m][r] = mnew;
        const float p0 = __builtin_amdgcn_exp2f((v0 - mnew) * L2E);
        const float p1 = __builtin_amdgcn_exp2f((v1 - mnew) * L2E);
        float sm = p0 + p1;
        sm += __shfl_xor(sm, 1);
        sm += __shfl_xor(sm, 2);
        sm += __shfl_xor(sm, 4);
        sm += __shfl_xor(sm, 8);
        lrow[m][r] = lrow[m][r] * alpha + sm;
#pragma unroll
        for (int ne = 0; ne < 4; ++ne) O[m][ne][r] *= alpha;
        // pack P(j=2c), P(j=2c+1) into one dword; wave-private buffer.
        const uint32_t pp = (uint32_t)f2bf(p0) | ((uint32_t)f2bf(p1) << 16);
        *(uint32_t*)&Pt[w][(m * 16 + g * 4 + r) * 40 + c * 2] = pp;
      }
    }

    // ensure this wave's P writes are visible before re-reading (wave-private)
    asm volatile("s_waitcnt lgkmcnt(0)" ::: "memory");
    __builtin_amdgcn_sched_barrier(0);

    // PV: O[32q x 64e] += P[32q x 32j] * V[32j x 64e]
    bf16x8 bv8[4];
#pragma unroll
    for (int ne = 0; ne < 4; ++ne) {
      const int e = ne * 16 + c;
      bv8[ne] = *(const bf16x8*)&Vt[e * 32 + ((g ^ ((e >> 1) & 3))) * 8];
    }
#pragma unroll
    for (int m = 0; m < 2; ++m) {
      const bf16x8 ap = *(const bf16x8*)&Pt[w][(m * 16 + c) * 40 + g * 8];
#pragma unroll
      for (int ne = 0; ne < 4; ++ne)
        O[m][ne] = __builtin_amdgcn_mfma_f32_16x16x32_bf16(ap, bv8[ne],
                                                           O[m][ne], 0, 0, 0);
    }
    __syncthreads();
  }

  // normalize + store concat layout [B,S,H*E] bf16
#pragma unroll
  for (int m = 0; m < 2; ++m)
#pragma unroll
    for (int r = 0; r < 4; ++r) {
      const float inv = 1.f / lrow[m][r];
      const int iq = q0 + m * 16 + g * 4 + r;
      const size_t ro = ((size_t)(bz * S_ + iq)) * 1024 + hh * 64;
#pragma unroll
      for (int ne = 0; ne < 4; ++ne)
        att[ro + ne * 16 + c] = f2bf(O[m][ne][r] * inv);
    }
}

// ---------------------------------------------------------------------------
// Output projection: out[4096x1024] = att(bf16) @ Wo + bo, -> f32 d_out
// ---------------------------------------------------------------------------
__global__ __launch_bounds__(256, 2)
void out_gemm(const unsigned short* __restrict__ att,
              const unsigned short* __restrict__ WoT,
              const float* __restrict__ bo, float* __restrict__ outp) {
  __shared__ unsigned short At[128 * 32];
  __shared__ unsigned short Bt[128 * 32];

  const int tid = threadIdx.x;
  const int lane = tid & 63;
  const int w = tid >> 6;
  const int g = lane >> 4, c = lane & 15;
  const int wm = w >> 1, wn = w & 1;
  const int m0 = blockIdx.x * 128;
  const int n0 = blockIdx.y * 128;

  f32x4 acc[4][4];
#pragma unroll
  for (int i = 0; i < 4; ++i)
#pragma unroll
    for (int j = 0; j < 4; ++j) acc[i][j] = fzero();

  for (int kt = 0; kt < 32; ++kt) {
    const int k0 = kt * 32;
#pragma unroll
    for (int u = 0; u < 2; ++u) {
      const int row = w * 32 + u * 16 + (lane >> 2);
      const int ch = (lane & 3) ^ ((row >> 1) & 3);
      gld_lds16(att + (size_t)(m0 + row) * 1024 + k0 + ch * 8,
                &At[(w * 32 + u * 16) * 32]);
      gld_lds16(WoT + (size_t)(n0 + row) * 1024 + k0 + ch * 8,
                &Bt[(w * 32 + u * 16) * 32]);
    }
    __syncthreads();

    bf16x8 af[4], bfr[4];
#pragma unroll
    for (int mi = 0; mi < 4; ++mi) {
      const int row = wm * 64 + mi * 16 + c;
      af[mi] = *(const bf16x8*)&At[row * 32 + ((g ^ ((row >> 1) & 3))) * 8];
    }
#pragma unroll
    for (int ni = 0; ni < 4; ++ni) {
      const int row = wn * 64 + ni * 16 + c;
      bfr[ni] = *(const bf16x8*)&Bt[row * 32 + ((g ^ ((row >> 1) & 3))) * 8];
    }
#pragma unroll
    for (int mi = 0; mi < 4; ++mi)
#pragma unroll
      for (int ni = 0; ni < 4; ++ni)
        acc[mi][ni] = __builtin_amdgcn_mfma_f32_16x16x32_bf16(af[mi], bfr[ni],
                                                              acc[mi][ni], 0, 0, 0);
    __syncthreads();
  }

#pragma unroll
  for (int ni = 0; ni < 4; ++ni) {
    const int colb = n0 + wn * 64 + ni * 16 + c;
    const float bc = bo[colb];
#pragma unroll
    for (int mi = 0; mi < 4; ++mi)
#pragma unroll
      for (int r = 0; r < 4; ++r) {
        const int row = m0 + wm * 64 + mi * 16 + g * 4 + r;
        outp[(size_t)row * 1024 + colb] = acc[mi][ni][r] + bc;
      }
  }
}

// ---------------------------------------------------------------------------
extern "C" void kernel_launch(void* const* d_in, const int* in_sizes, int n_in,
                              void* d_out, int out_size, void* d_ws, size_t ws_size,
                              hipStream_t stream) {
  const float* Q  = (const float*)d_in[0];
  const float* T  = (const float*)d_in[1];
  const float* V  = (const float*)d_in[2];
  const float* Wq = (const float*)d_in[3];
  const float* bq = (const float*)d_in[4];
  const float* Wk = (const float*)d_in[5];
  const float* bk = (const float*)d_in[6];
  const float* Wv = (const float*)d_in[7];
  const float* bv = (const float*)d_in[8];
  const float* Wo = (const float*)d_in[9];
  const float* bo = (const float*)d_in[10];

  const size_t MB = 1024ull * 1024ull;
  if (ws_size < 40 * MB) return;  // need 40 MB scratch; clean fail otherwise

  uint8_t* ws = (uint8_t*)d_ws;
  unsigned short* Wt  = (unsigned short*)(ws);            // 8MB: WqT,WkT,WvT,WoT
  unsigned short* qb  = (unsigned short*)(ws + 8 * MB);   // 8MB  [B,H,S,E]
  unsigned short* kb  = (unsigned short*)(ws + 16 * MB);  // 8MB  [B,H,S,E]
  unsigned short* vtb = (unsigned short*)(ws + 24 * MB);  // 8MB  [B,H,E,S]
  unsigned short* attb = (unsigned short*)(ws + 32 * MB); // 8MB  [B,S,H*E]

  prep_weights<<<dim3(512, 1, 4), 256, 0, stream>>>(Wq, Wk, Wv, Wo, Wt);
  proj_gemm<<<dim3(32, 24), 256, 0, stream>>>(Q, T, V, Wt, bq, bk, bv, qb, kb, vtb);
  attn_kernel<<<dim3(16, 16, 2), 256, 0, stream>>>(qb, kb, vtb, attb);
  out_gemm<<<dim3(32, 8), 256, 0, stream>>>(attb, Wt + 3ull * 1024ull * 1024ull,
                                            bo, (float*)d_out);
}

// Round 3
// 167.631 us; speedup vs baseline: 1.4550x; 1.4550x over previous
//
#include <hip/hip_runtime.h>
#include <stdint.h>

// MultiHeadAttentionLayer: bf16-MFMA pipeline, f32 output.
//   prep_weights: Wq/Wk/Wv ([H,D,E] f32) -> W^T bf16 [H*E][D]; Wo -> Wo^T bf16
//   proj_gemm:    q,k = [B,H,S,E] bf16; v stored transposed [B,H,E,S] bf16
//   attn_kernel:  flash-style, SWAPPED QK^T (S^T=K*Q) so row-reduce is in-lane
//   out_gemm:     att[4096x1024] @ Wo^T + bo -> d_out (f32)

typedef __attribute__((ext_vector_type(8))) short bf16x8;
typedef __attribute__((ext_vector_type(4))) float f32x4;

#define DEVFN static __device__ __forceinline__

static constexpr int S_ = 2048;
static constexpr int H_ = 16;

DEVFN unsigned short f2bf(float x) {
  union { float f; uint32_t u; } v; v.f = x;
  const uint32_t r = v.u + 0x7fffu + ((v.u >> 16) & 1u);  // RNE
  return (unsigned short)(r >> 16);
}

DEVFN uint32_t pkbf(float a, float b) {
  return (uint32_t)f2bf(a) | ((uint32_t)f2bf(b) << 16);
}

DEVFN f32x4 fzero() { f32x4 v = {0.f, 0.f, 0.f, 0.f}; return v; }

// global -> LDS direct copy, 16B per lane; LDS dest must be wave-uniform base.
DEVFN void gld_lds16(const void* g, void* lds) {
  __builtin_amdgcn_global_load_lds(
      (const __attribute__((address_space(1))) void*)g,
      (__attribute__((address_space(3))) void*)lds, 16, 0, 0);
}

// ---------------------------------------------------------------------------
// Weight prep: dst[c][d] = W[h=c>>6][d][e=c&63] (z<3) or Wo[d][c] (z==3), bf16
// ---------------------------------------------------------------------------
__global__ void prep_weights(const float* __restrict__ Wq, const float* __restrict__ Wk,
                             const float* __restrict__ Wv, const float* __restrict__ Wo,
                             unsigned short* __restrict__ dstBase) {
  const int z = blockIdx.z;
  const float* src = (z == 0) ? Wq : (z == 1) ? Wk : (z == 2) ? Wv : Wo;
  unsigned short* dst = dstBase + (size_t)z * (1024u * 1024u);
  const int idx = blockIdx.x * 256 + threadIdx.x;  // 131072 threads
  const int c = idx & 1023;
  const int d0 = (idx >> 10) << 3;
  unsigned short hv[8];
#pragma unroll
  for (int t = 0; t < 8; ++t) {
    const int d = d0 + t;
    const float v = (z < 3) ? src[(size_t)((c >> 6) * 1024 + d) * 64 + (c & 63)]
                            : src[(size_t)d * 1024 + c];
    hv[t] = f2bf(v);
  }
  *(uint4*)(dst + (size_t)c * 1024 + d0) = *(const uint4*)hv;
}

// ---------------------------------------------------------------------------
// QKV projection GEMM: C[4096x1024] = A(f32) * W^T(bf16), 128x128 tile, BK=32.
// ---------------------------------------------------------------------------
__global__ __launch_bounds__(256, 2)
void proj_gemm(const float* __restrict__ Qm, const float* __restrict__ Tm,
               const float* __restrict__ Vm, const unsigned short* __restrict__ Wt,
               const float* __restrict__ bq, const float* __restrict__ bk,
               const float* __restrict__ bv, unsigned short* __restrict__ qb,
               unsigned short* __restrict__ kb, unsigned short* __restrict__ vtb) {
  __shared__ unsigned short At[128 * 32];
  __shared__ unsigned short Bt[128 * 32];

  const int tid = threadIdx.x;
  const int lane = tid & 63;
  const int w = tid >> 6;
  const int g = lane >> 4, c = lane & 15;
  const int wm = w >> 1, wn = w & 1;

  const int m0 = blockIdx.x * 128;
  const int proj = blockIdx.y >> 3;
  const int n0 = (blockIdx.y & 7) * 128;

  const float* Asrc = (proj == 0) ? Qm : (proj == 1) ? Tm : Vm;
  const unsigned short* W = Wt + (size_t)proj * (1024u * 1024u);

  f32x4 acc[4][4];
#pragma unroll
  for (int i = 0; i < 4; ++i)
#pragma unroll
    for (int j = 0; j < 4; ++j) acc[i][j] = fzero();

  const int ar = tid >> 1;  // A row 0..127
  const int ah = tid & 1;   // which 16-f32 half of the 32-wide k slice

  for (int kt = 0; kt < 32; ++kt) {
    const int k0 = kt * 32;
    {
      const float* s = Asrc + (size_t)(m0 + ar) * 1024 + k0 + ah * 16;
      const float4 f0 = ((const float4*)s)[0];
      const float4 f1 = ((const float4*)s)[1];
      const float4 f2 = ((const float4*)s)[2];
      const float4 f3 = ((const float4*)s)[3];
      unsigned short hv[16];
      hv[0] = f2bf(f0.x); hv[1] = f2bf(f0.y); hv[2] = f2bf(f0.z); hv[3] = f2bf(f0.w);
      hv[4] = f2bf(f1.x); hv[5] = f2bf(f1.y); hv[6] = f2bf(f1.z); hv[7] = f2bf(f1.w);
      hv[8] = f2bf(f2.x); hv[9] = f2bf(f2.y); hv[10] = f2bf(f2.z); hv[11] = f2bf(f2.w);
      hv[12] = f2bf(f3.x); hv[13] = f2bf(f3.y); hv[14] = f2bf(f3.z); hv[15] = f2bf(f3.w);
      const int swz = (ar >> 1) & 3;
      *(uint4*)&At[ar * 32 + ((ah * 2 + 0) ^ swz) * 8] = *(const uint4*)&hv[0];
      *(uint4*)&At[ar * 32 + ((ah * 2 + 1) ^ swz) * 8] = *(const uint4*)&hv[8];
    }
#pragma unroll
    for (int u = 0; u < 2; ++u) {
      const int row = w * 32 + u * 16 + (lane >> 2);
      const int ch = (lane & 3) ^ ((row >> 1) & 3);
      gld_lds16(W + (size_t)(n0 + row) * 1024 + k0 + ch * 8,
                &Bt[(w * 32 + u * 16) * 32]);
    }
    __syncthreads();

    bf16x8 af[4], bfr[4];
#pragma unroll
    for (int mi = 0; mi < 4; ++mi) {
      const int row = wm * 64 + mi * 16 + c;
      af[mi] = *(const bf16x8*)&At[row * 32 + ((g ^ ((row >> 1) & 3))) * 8];
    }
#pragma unroll
    for (int ni = 0; ni < 4; ++ni) {
      const int row = wn * 64 + ni * 16 + c;
      bfr[ni] = *(const bf16x8*)&Bt[row * 32 + ((g ^ ((row >> 1) & 3))) * 8];
    }
#pragma unroll
    for (int mi = 0; mi < 4; ++mi)
#pragma unroll
      for (int ni = 0; ni < 4; ++ni)
        acc[mi][ni] = __builtin_amdgcn_mfma_f32_16x16x32_bf16(af[mi], bfr[ni],
                                                              acc[mi][ni], 0, 0, 0);
    __syncthreads();
  }

  const float* bias = (proj == 0) ? bq : (proj == 1) ? bk : bv;
#pragma unroll
  for (int ni = 0; ni < 4; ++ni) {
    const int colb = n0 + wn * 64 + ni * 16 + c;  // 0..1023 = h*64+e
    const float bc = bias[colb];
    const int hh = colb >> 6, e = colb & 63;
#pragma unroll
    for (int mi = 0; mi < 4; ++mi) {
#pragma unroll
      for (int r = 0; r < 4; ++r) {
        const int row = m0 + wm * 64 + mi * 16 + g * 4 + r;  // b*S+s
        const int bb = row >> 11, s = row & 2047;
        const float val = acc[mi][ni][r] + bc;
        if (proj < 2) {
          unsigned short* d = (proj == 0) ? qb : kb;
          d[(((size_t)(bb * H_ + hh)) * S_ + s) * 64 + e] = f2bf(val);
        } else {  // v stored transposed per head: [B,H,E,S]
          vtb[(((size_t)(bb * H_ + hh)) * 64 + e) * S_ + s] = f2bf(val);
        }
      }
    }
  }
}

// ---------------------------------------------------------------------------
// Flash attention v2. 1024 blocks (XCD-swizzled), 4 waves x 16 q-rows = 64 q.
// KVBLK = 64. Swapped QK^T: S^T[kv][q] = mfma(A=K, B=Q) -> lane owns q = lane&15,
// its 16 S values (kv = 16*mi + 4*g + r) are in-lane -> reduce = 15 VALU + 2 shfl.
// K tile [64kv][64E], V^T tile [64e][64kv], P [16q][64kv] per wave; all LDS
// rows are 8 x 16B chunks, XOR-swizzled by (row&7) (write side pre-swizzled).
// ---------------------------------------------------------------------------
__global__ __launch_bounds__(256, 4)
void attn_kernel(const unsigned short* __restrict__ qb,
                 const unsigned short* __restrict__ kb,
                 const unsigned short* __restrict__ vtb,
                 unsigned short* __restrict__ att) {
  __shared__ unsigned short Kt[64 * 64];
  __shared__ unsigned short Vt[64 * 64];
  __shared__ unsigned short Pt[4][16 * 64];

  const int tid = threadIdx.x;
  const int lane = tid & 63;
  const int w = tid >> 6;
  const int g = lane >> 4, c = lane & 15;

  // bijective XCD remap: consecutive logical blocks land on the same XCD,
  // so each XCD's L2 caches only ~4 heads' K/V (2MB < 4MB).
  const int orig = blockIdx.x;                    // 0..1023
  const int logical = ((orig & 7) << 7) | (orig >> 3);
  const int qblk = logical & 31;                  // 32 q-blocks of 64 rows
  const int bh = logical >> 5;                    // b*16+h, 0..31
  const int hh = bh & 15, bz = bh >> 4;

  const int q0w = qblk * 64 + w * 16;             // wave's 16 q rows
  const unsigned short* qh = qb + (size_t)bh * S_ * 64;
  const unsigned short* kh = kb + (size_t)bh * S_ * 64;
  const unsigned short* vh = vtb + (size_t)bh * 64 * S_;

  // Q B-fragments (col=q=c, k=E=t*32+g*8), held all kernel.
  bf16x8 aq[2];
#pragma unroll
  for (int t = 0; t < 2; ++t)
    aq[t] = *(const bf16x8*)&qh[(size_t)(q0w + c) * 64 + t * 32 + g * 8];

  f32x4 O[4];  // O[ne]: rows q=4g+r, cols e=ne*16+c
#pragma unroll
  for (int ne = 0; ne < 4; ++ne) O[ne] = fzero();
  float m_old = -1e30f, l = 0.f;  // softmax state for q = c (dup across g)

  constexpr float L2E = 1.4426950408889634f;
  const int iq = q0w + c;

  for (int jt = 0; jt < 32; ++jt) {
    const int j0 = jt * 64;
    // stage K [64 kv][64 E]: wave w covers rows w*8.. (+32 for u=1)
#pragma unroll
    for (int u = 0; u < 2; ++u) {
      const int row = u * 32 + w * 8 + (lane >> 3);
      gld_lds16(kh + (size_t)(j0 + row) * 64 + ((lane & 7) ^ (row & 7)) * 8,
                &Kt[(u * 32 + w * 8) * 64]);
    }
    // stage V^T [64 e][64 kv]
#pragma unroll
    for (int u = 0; u < 2; ++u) {
      const int e = u * 32 + w * 8 + (lane >> 3);
      gld_lds16(vh + (size_t)e * S_ + j0 + ((lane & 7) ^ (e & 7)) * 8,
                &Vt[(u * 32 + w * 8) * 64]);
    }
    __syncthreads();

    // QK^T swapped: sa[mi] = S^T rows kv=16mi+4g+r, col q=c
    f32x4 sa[4];
#pragma unroll
    for (int mi = 0; mi < 4; ++mi) sa[mi] = fzero();
#pragma unroll
    for (int ks = 0; ks < 2; ++ks) {
#pragma unroll
      for (int mi = 0; mi < 4; ++mi) {
        const int row = mi * 16 + c;
        const bf16x8 ka =
            *(const bf16x8*)&Kt[row * 64 + ((ks * 4 + g) ^ (row & 7)) * 8];
        sa[mi] = __builtin_amdgcn_mfma_f32_16x16x32_bf16(ka, aq[ks], sa[mi], 0, 0, 0);
      }
    }

    // threshold + upper-tri(+1) + scale; logits in p[]
    float p[16];
    const bool allUp = (j0 >= q0w + 16);
    const bool noneUp = (j0 + 63 <= q0w);
#pragma unroll
    for (int mi = 0; mi < 4; ++mi)
#pragma unroll
      for (int r = 0; r < 4; ++r) {
        float v = sa[mi][r];
        v = (v > 0.1f) ? v : 0.f;
        float b;
        if (allUp) b = 0.125f;
        else if (noneUp) b = 0.f;
        else b = (j0 + mi * 16 + g * 4 + r > iq) ? 0.125f : 0.f;
        p[mi * 4 + r] = __builtin_fmaf(v, 0.125f, b);
      }

    // row max: in-lane 16 -> 1, then across g (xor 16, 32)
    float mx = fmaxf(p[0], p[1]);
#pragma unroll
    for (int i = 2; i < 16; ++i) mx = fmaxf(mx, p[i]);
    mx = fmaxf(mx, __shfl_xor(mx, 16));
    mx = fmaxf(mx, __shfl_xor(mx, 32));

    const float mnew = fmaxf(m_old, mx);
    if (__any(mnew > m_old)) {  // wave-uniform rescale (skipped once maxes settle)
      const float alpha = __builtin_amdgcn_exp2f((m_old - mnew) * L2E);
      const int base = (lane >> 2) & 12;  // = 4*g
      float ar[4];
#pragma unroll
      for (int r = 0; r < 4; ++r) ar[r] = __shfl(alpha, base + r);
#pragma unroll
      for (int ne = 0; ne < 4; ++ne)
#pragma unroll
        for (int r = 0; r < 4; ++r) O[ne][r] *= ar[r];
      l *= alpha;
      m_old = mnew;
    }

    float ssum = 0.f;
#pragma unroll
    for (int i = 0; i < 16; ++i) {
      p[i] = __builtin_amdgcn_exp2f((p[i] - m_old) * L2E);
      ssum += p[i];
    }
    ssum += __shfl_xor(ssum, 16);
    ssum += __shfl_xor(ssum, 32);
    l += ssum;

    // pack P -> bf16 pairs, swizzled ds_write_b64 into wave-private Pt
#pragma unroll
    for (int mi = 0; mi < 4; ++mi) {
      uint2 d;
      d.x = pkbf(p[mi * 4 + 0], p[mi * 4 + 1]);
      d.y = pkbf(p[mi * 4 + 2], p[mi * 4 + 3]);
      const int pc = (2 * mi + (g >> 1)) ^ (c & 7);
      *(uint2*)&Pt[w][c * 64 + pc * 8 + (g & 1) * 4] = d;
    }
    asm volatile("s_waitcnt lgkmcnt(0)" ::: "memory");
    __builtin_amdgcn_sched_barrier(0);

    // PV: O[q][e] += P^T[q][kv] * V[kv][e]
#pragma unroll
    for (int ks = 0; ks < 2; ++ks) {
      const bf16x8 pa =
          *(const bf16x8*)&Pt[w][c * 64 + (((ks * 4 + g) ^ (c & 7))) * 8];
#pragma unroll
      for (int ne = 0; ne < 4; ++ne) {
        const int e = ne * 16 + c;
        const bf16x8 bv8 =
            *(const bf16x8*)&Vt[e * 64 + ((ks * 4 + g) ^ (e & 7)) * 8];
        O[ne] = __builtin_amdgcn_mfma_f32_16x16x32_bf16(pa, bv8, O[ne], 0, 0, 0);
      }
    }
    __syncthreads();
  }

  // normalize + store concat layout [B,S,H*E] bf16
  const float invl = 1.f / l;
  const int base = (lane >> 2) & 12;
  float il[4];
#pragma unroll
  for (int r = 0; r < 4; ++r) il[r] = __shfl(invl, base + r);
#pragma unroll
  for (int r = 0; r < 4; ++r) {
    const int qg = q0w + g * 4 + r;
    const size_t ro = ((size_t)(bz * S_ + qg)) * 1024 + hh * 64;
#pragma unroll
    for (int ne = 0; ne < 4; ++ne)
      att[ro + ne * 16 + c] = f2bf(O[ne][r] * il[r]);
  }
}

// ---------------------------------------------------------------------------
// Output projection: out[4096x1024] = att(bf16) @ Wo + bo, -> f32 d_out
// ---------------------------------------------------------------------------
__global__ __launch_bounds__(256, 2)
void out_gemm(const unsigned short* __restrict__ att,
              const unsigned short* __restrict__ WoT,
              const float* __restrict__ bo, float* __restrict__ outp) {
  __shared__ unsigned short At[128 * 32];
  __shared__ unsigned short Bt[128 * 32];

  const int tid = threadIdx.x;
  const int lane = tid & 63;
  const int w = tid >> 6;
  const int g = lane >> 4, c = lane & 15;
  const int wm = w >> 1, wn = w & 1;
  const int m0 = blockIdx.x * 128;
  const int n0 = blockIdx.y * 128;

  f32x4 acc[4][4];
#pragma unroll
  for (int i = 0; i < 4; ++i)
#pragma unroll
    for (int j = 0; j < 4; ++j) acc[i][j] = fzero();

  for (int kt = 0; kt < 32; ++kt) {
    const int k0 = kt * 32;
#pragma unroll
    for (int u = 0; u < 2; ++u) {
      const int row = w * 32 + u * 16 + (lane >> 2);
      const int ch = (lane & 3) ^ ((row >> 1) & 3);
      gld_lds16(att + (size_t)(m0 + row) * 1024 + k0 + ch * 8,
                &At[(w * 32 + u * 16) * 32]);
      gld_lds16(WoT + (size_t)(n0 + row) * 1024 + k0 + ch * 8,
                &Bt[(w * 32 + u * 16) * 32]);
    }
    __syncthreads();

    bf16x8 af[4], bfr[4];
#pragma unroll
    for (int mi = 0; mi < 4; ++mi) {
      const int row = wm * 64 + mi * 16 + c;
      af[mi] = *(const bf16x8*)&At[row * 32 + ((g ^ ((row >> 1) & 3))) * 8];
    }
#pragma unroll
    for (int ni = 0; ni < 4; ++ni) {
      const int row = wn * 64 + ni * 16 + c;
      bfr[ni] = *(const bf16x8*)&Bt[row * 32 + ((g ^ ((row >> 1) & 3))) * 8];
    }
#pragma unroll
    for (int mi = 0; mi < 4; ++mi)
#pragma unroll
      for (int ni = 0; ni < 4; ++ni)
        acc[mi][ni] = __builtin_amdgcn_mfma_f32_16x16x32_bf16(af[mi], bfr[ni],
                                                              acc[mi][ni], 0, 0, 0);
    __syncthreads();
  }

#pragma unroll
  for (int ni = 0; ni < 4; ++ni) {
    const int colb = n0 + wn * 64 + ni * 16 + c;
    const float bc = bo[colb];
#pragma unroll
    for (int mi = 0; mi < 4; ++mi)
#pragma unroll
      for (int r = 0; r < 4; ++r) {
        const int row = m0 + wm * 64 + mi * 16 + g * 4 + r;
        outp[(size_t)row * 1024 + colb] = acc[mi][ni][r] + bc;
      }
  }
}

// ---------------------------------------------------------------------------
extern "C" void kernel_launch(void* const* d_in, const int* in_sizes, int n_in,
                              void* d_out, int out_size, void* d_ws, size_t ws_size,
                              hipStream_t stream) {
  const float* Q  = (const float*)d_in[0];
  const float* T  = (const float*)d_in[1];
  const float* V  = (const float*)d_in[2];
  const float* Wq = (const float*)d_in[3];
  const float* bq = (const float*)d_in[4];
  const float* Wk = (const float*)d_in[5];
  const float* bk = (const float*)d_in[6];
  const float* Wv = (const float*)d_in[7];
  const float* bv = (const float*)d_in[8];
  const float* Wo = (const float*)d_in[9];
  const float* bo = (const float*)d_in[10];

  const size_t MB = 1024ull * 1024ull;
  if (ws_size < 40 * MB) return;  // need 40 MB scratch; clean fail otherwise

  uint8_t* ws = (uint8_t*)d_ws;
  unsigned short* Wt  = (unsigned short*)(ws);            // 8MB: WqT,WkT,WvT,WoT
  unsigned short* qb  = (unsigned short*)(ws + 8 * MB);   // 8MB  [B,H,S,E]
  unsigned short* kb  = (unsigned short*)(ws + 16 * MB);  // 8MB  [B,H,S,E]
  unsigned short* vtb = (unsigned short*)(ws + 24 * MB);  // 8MB  [B,H,E,S]
  unsigned short* attb = (unsigned short*)(ws + 32 * MB); // 8MB  [B,S,H*E]

  prep_weights<<<dim3(512, 1, 4), 256, 0, stream>>>(Wq, Wk, Wv, Wo, Wt);
  proj_gemm<<<dim3(32, 24), 256, 0, stream>>>(Q, T, V, Wt, bq, bk, bv, qb, kb, vtb);
  attn_kernel<<<dim3(1024), 256, 0, stream>>>(qb, kb, vtb, attb);
  out_gemm<<<dim3(32, 8), 256, 0, stream>>>(attb, Wt + 3ull * 1024ull * 1024ull,
                                            bo, (float*)d_out);
}

// Round 4
// 142.681 us; speedup vs baseline: 1.7094x; 1.1749x over previous
//
#include <hip/hip_runtime.h>
#include <stdint.h>

// MultiHeadAttentionLayer: bf16-MFMA pipeline, f32 output.
//   prep_weights: Wq/Wk/Wv ([H,D,E] f32) -> W^T bf16 [H*E][D]; Wo -> Wo^T bf16
//   proj_gemm:    q,k = [B,H,S,E] bf16; v stored transposed [B,H,E,S] bf16
//   attn_kernel:  flash-style, swapped QK^T, STATIC-max softmax (logits bounded),
//                 double-buffered K/V staging, cvt_pk P pack
//   out_gemm:     att[4096x1024] @ Wo^T + bo -> d_out (f32)

typedef __attribute__((ext_vector_type(8))) short bf16x8;
typedef __attribute__((ext_vector_type(4))) float f32x4;

#define DEVFN static __device__ __forceinline__

static constexpr int S_ = 2048;
static constexpr int H_ = 16;

DEVFN unsigned short f2bf(float x) {
  union { float f; uint32_t u; } v; v.f = x;
  const uint32_t r = v.u + 0x7fffu + ((v.u >> 16) & 1u);  // RNE
  return (unsigned short)(r >> 16);
}

DEVFN f32x4 fzero() { f32x4 v = {0.f, 0.f, 0.f, 0.f}; return v; }

// global -> LDS direct copy, 16B per lane; LDS dest must be wave-uniform base.
DEVFN void gld_lds16(const void* g, void* lds) {
  __builtin_amdgcn_global_load_lds(
      (const __attribute__((address_space(1))) void*)g,
      (__attribute__((address_space(3))) void*)lds, 16, 0, 0);
}

// ---------------------------------------------------------------------------
// Weight prep: dst[c][d] = W[h=c>>6][d][e=c&63] (z<3) or Wo[d][c] (z==3), bf16
// ---------------------------------------------------------------------------
__global__ void prep_weights(const float* __restrict__ Wq, const float* __restrict__ Wk,
                             const float* __restrict__ Wv, const float* __restrict__ Wo,
                             unsigned short* __restrict__ dstBase) {
  const int z = blockIdx.z;
  const float* src = (z == 0) ? Wq : (z == 1) ? Wk : (z == 2) ? Wv : Wo;
  unsigned short* dst = dstBase + (size_t)z * (1024u * 1024u);
  const int idx = blockIdx.x * 256 + threadIdx.x;  // 131072 threads
  const int c = idx & 1023;
  const int d0 = (idx >> 10) << 3;
  unsigned short hv[8];
#pragma unroll
  for (int t = 0; t < 8; ++t) {
    const int d = d0 + t;
    const float v = (z < 3) ? src[(size_t)((c >> 6) * 1024 + d) * 64 + (c & 63)]
                            : src[(size_t)d * 1024 + c];
    hv[t] = f2bf(v);
  }
  *(uint4*)(dst + (size_t)c * 1024 + d0) = *(const uint4*)hv;
}

// ---------------------------------------------------------------------------
// QKV projection GEMM: C[4096x1024] = A(f32) * W^T(bf16), 128x128 tile, BK=32.
// ---------------------------------------------------------------------------
__global__ __launch_bounds__(256, 2)
void proj_gemm(const float* __restrict__ Qm, const float* __restrict__ Tm,
               const float* __restrict__ Vm, const unsigned short* __restrict__ Wt,
               const float* __restrict__ bq, const float* __restrict__ bk,
               const float* __restrict__ bv, unsigned short* __restrict__ qb,
               unsigned short* __restrict__ kb, unsigned short* __restrict__ vtb) {
  __shared__ unsigned short At[128 * 32];
  __shared__ unsigned short Bt[128 * 32];

  const int tid = threadIdx.x;
  const int lane = tid & 63;
  const int w = tid >> 6;
  const int g = lane >> 4, c = lane & 15;
  const int wm = w >> 1, wn = w & 1;

  const int m0 = blockIdx.x * 128;
  const int proj = blockIdx.y >> 3;
  const int n0 = (blockIdx.y & 7) * 128;

  const float* Asrc = (proj == 0) ? Qm : (proj == 1) ? Tm : Vm;
  const unsigned short* W = Wt + (size_t)proj * (1024u * 1024u);

  f32x4 acc[4][4];
#pragma unroll
  for (int i = 0; i < 4; ++i)
#pragma unroll
    for (int j = 0; j < 4; ++j) acc[i][j] = fzero();

  const int ar = tid >> 1;  // A row 0..127
  const int ah = tid & 1;   // which 16-f32 half of the 32-wide k slice

  for (int kt = 0; kt < 32; ++kt) {
    const int k0 = kt * 32;
    {
      const float* s = Asrc + (size_t)(m0 + ar) * 1024 + k0 + ah * 16;
      const float4 f0 = ((const float4*)s)[0];
      const float4 f1 = ((const float4*)s)[1];
      const float4 f2 = ((const float4*)s)[2];
      const float4 f3 = ((const float4*)s)[3];
      unsigned short hv[16];
      hv[0] = f2bf(f0.x); hv[1] = f2bf(f0.y); hv[2] = f2bf(f0.z); hv[3] = f2bf(f0.w);
      hv[4] = f2bf(f1.x); hv[5] = f2bf(f1.y); hv[6] = f2bf(f1.z); hv[7] = f2bf(f1.w);
      hv[8] = f2bf(f2.x); hv[9] = f2bf(f2.y); hv[10] = f2bf(f2.z); hv[11] = f2bf(f2.w);
      hv[12] = f2bf(f3.x); hv[13] = f2bf(f3.y); hv[14] = f2bf(f3.z); hv[15] = f2bf(f3.w);
      const int swz = (ar >> 1) & 3;
      *(uint4*)&At[ar * 32 + ((ah * 2 + 0) ^ swz) * 8] = *(const uint4*)&hv[0];
      *(uint4*)&At[ar * 32 + ((ah * 2 + 1) ^ swz) * 8] = *(const uint4*)&hv[8];
    }
#pragma unroll
    for (int u = 0; u < 2; ++u) {
      const int row = w * 32 + u * 16 + (lane >> 2);
      const int ch = (lane & 3) ^ ((row >> 1) & 3);
      gld_lds16(W + (size_t)(n0 + row) * 1024 + k0 + ch * 8,
                &Bt[(w * 32 + u * 16) * 32]);
    }
    __syncthreads();

    bf16x8 af[4], bfr[4];
#pragma unroll
    for (int mi = 0; mi < 4; ++mi) {
      const int row = wm * 64 + mi * 16 + c;
      af[mi] = *(const bf16x8*)&At[row * 32 + ((g ^ ((row >> 1) & 3))) * 8];
    }
#pragma unroll
    for (int ni = 0; ni < 4; ++ni) {
      const int row = wn * 64 + ni * 16 + c;
      bfr[ni] = *(const bf16x8*)&Bt[row * 32 + ((g ^ ((row >> 1) & 3))) * 8];
    }
#pragma unroll
    for (int mi = 0; mi < 4; ++mi)
#pragma unroll
      for (int ni = 0; ni < 4; ++ni)
        acc[mi][ni] = __builtin_amdgcn_mfma_f32_16x16x32_bf16(af[mi], bfr[ni],
                                                              acc[mi][ni], 0, 0, 0);
    __syncthreads();
  }

  const float* bias = (proj == 0) ? bq : (proj == 1) ? bk : bv;
#pragma unroll
  for (int ni = 0; ni < 4; ++ni) {
    const int colb = n0 + wn * 64 + ni * 16 + c;  // 0..1023 = h*64+e
    const float bc = bias[colb];
    const int hh = colb >> 6, e = colb & 63;
#pragma unroll
    for (int mi = 0; mi < 4; ++mi) {
#pragma unroll
      for (int r = 0; r < 4; ++r) {
        const int row = m0 + wm * 64 + mi * 16 + g * 4 + r;  // b*S+s
        const int bb = row >> 11, s = row & 2047;
        const float val = acc[mi][ni][r] + bc;
        if (proj < 2) {
          unsigned short* d = (proj == 0) ? qb : kb;
          d[(((size_t)(bb * H_ + hh)) * S_ + s) * 64 + e] = f2bf(val);
        } else {  // v stored transposed per head: [B,H,E,S]
          vtb[(((size_t)(bb * H_ + hh)) * 64 + e) * S_ + s] = f2bf(val);
        }
      }
    }
  }
}

// ---------------------------------------------------------------------------
// Flash attention v3. 1024 blocks (XCD-swizzled), 4 waves x 16 q-rows = 64 q.
// KVBLK=64, double-buffered K/V. Swapped QK^T: lane owns q=c, 16 in-lane kv.
// STATIC max: logits bounded (<= ~7), so exp never overflows -> no online max,
// no O rescale, l reduced once in the epilogue. P pack via v_cvt_pk_bf16_f32.
// ---------------------------------------------------------------------------
__global__ __launch_bounds__(256, 4)
void attn_kernel(const unsigned short* __restrict__ qb,
                 const unsigned short* __restrict__ kb,
                 const unsigned short* __restrict__ vtb,
                 unsigned short* __restrict__ att) {
  __shared__ unsigned short Kt[2][64 * 64];
  __shared__ unsigned short Vt[2][64 * 64];
  __shared__ unsigned short Pt[4][16 * 64];

  const int tid = threadIdx.x;
  const int lane = tid & 63;
  const int w = tid >> 6;
  const int g = lane >> 4, c = lane & 15;

  // bijective XCD remap: consecutive logical blocks share an XCD's L2.
  const int orig = blockIdx.x;                    // 0..1023
  const int logical = ((orig & 7) << 7) | (orig >> 3);
  const int qblk = logical & 31;                  // 32 q-blocks of 64 rows
  const int bh = logical >> 5;                    // b*16+h, 0..31
  const int hh = bh & 15, bz = bh >> 4;

  const int q0w = qblk * 64 + w * 16;             // wave's 16 q rows
  const unsigned short* qh = qb + (size_t)bh * S_ * 64;
  const unsigned short* kh = kb + (size_t)bh * S_ * 64;
  const unsigned short* vh = vtb + (size_t)bh * 64 * S_;

  // Q B-fragments (col=q=c, k=E=t*32+g*8), held all kernel.
  bf16x8 aq[2];
#pragma unroll
  for (int t = 0; t < 2; ++t)
    aq[t] = *(const bf16x8*)&qh[(size_t)(q0w + c) * 64 + t * 32 + g * 8];

  f32x4 O[4];  // O[ne]: rows q=4g+r, cols e=ne*16+c
#pragma unroll
  for (int ne = 0; ne < 4; ++ne) O[ne] = fzero();
  float l_lane = 0.f;  // partial softmax denom for q=c (this lane's 16 kv/iter)

  constexpr float L2E = 1.4426950408889634f;
  const float S2 = 0.125f * L2E;  // score scale folded into exp2 space
  const float B2 = 0.125f * L2E;  // upper-tri +1 bias folded (=(+1)/8*L2E)
  const int iq = q0w + c;

  const int srow = w * 8 + (lane >> 3);  // staging row within 32-row half
  const int sch = lane & 7;              // staging 16B chunk

  {  // prologue: stage tile 0 into buffer 0
#pragma unroll
    for (int u = 0; u < 2; ++u) {
      const int row = u * 32 + srow;
      gld_lds16(kh + (size_t)row * 64 + (sch ^ (row & 7)) * 8,
                &Kt[0][(u * 32 + w * 8) * 64]);
      gld_lds16(vh + (size_t)row * S_ + (sch ^ (row & 7)) * 8,
                &Vt[0][(u * 32 + w * 8) * 64]);
    }
  }
  __syncthreads();  // drains vmcnt before barrier (compiler semantics)

  for (int jt = 0; jt < 32; ++jt) {
    const int cur = jt & 1;
    const int j0 = jt * 64;

    if (jt < 31) {  // issue next tile's staging early; latency hides under compute
      const int jn = j0 + 64;
#pragma unroll
      for (int u = 0; u < 2; ++u) {
        const int row = u * 32 + srow;
        gld_lds16(kh + (size_t)(jn + row) * 64 + (sch ^ (row & 7)) * 8,
                  &Kt[cur ^ 1][(u * 32 + w * 8) * 64]);
        gld_lds16(vh + (size_t)row * S_ + jn + (sch ^ (row & 7)) * 8,
                  &Vt[cur ^ 1][(u * 32 + w * 8) * 64]);
      }
    }

    // QK^T swapped: sa[mi] = S^T rows kv=16mi+4g+r, col q=c
    f32x4 sa[4];
#pragma unroll
    for (int mi = 0; mi < 4; ++mi) sa[mi] = fzero();
#pragma unroll
    for (int ks = 0; ks < 2; ++ks) {
#pragma unroll
      for (int mi = 0; mi < 4; ++mi) {
        const int row = mi * 16 + c;
        const bf16x8 ka =
            *(const bf16x8*)&Kt[cur][row * 64 + ((ks * 4 + g) ^ (row & 7)) * 8];
        sa[mi] = __builtin_amdgcn_mfma_f32_16x16x32_bf16(ka, aq[ks], sa[mi], 0, 0, 0);
      }
    }

    // threshold + upper-tri bias + scale, all folded into the exp2 argument
    float pe[16];
    const bool allUp = (j0 >= q0w + 16);
    const bool noneUp = (j0 + 63 <= q0w);
    if (allUp || noneUp) {  // wave-uniform bias (~97% of tiles)
      const float bb = allUp ? B2 : 0.f;
#pragma unroll
      for (int i = 0; i < 16; ++i) {
        const float v = sa[i >> 2][i & 3];
        const float arg = (v > 0.1f) ? __builtin_fmaf(v, S2, bb) : bb;
        pe[i] = __builtin_amdgcn_exp2f(arg);
      }
    } else {  // diagonal tile: per-element bias
#pragma unroll
      for (int mi = 0; mi < 4; ++mi)
#pragma unroll
        for (int r = 0; r < 4; ++r) {
          const float v = sa[mi][r];
          const float bb = (j0 + mi * 16 + g * 4 + r > iq) ? B2 : 0.f;
          const float arg = (v > 0.1f) ? __builtin_fmaf(v, S2, bb) : bb;
          pe[mi * 4 + r] = __builtin_amdgcn_exp2f(arg);
        }
    }

    // in-lane partial row sum (cross-g reduction deferred to epilogue)
    {
      float s01 = pe[0] + pe[1], s23 = pe[2] + pe[3];
      float s45 = pe[4] + pe[5], s67 = pe[6] + pe[7];
      float s89 = pe[8] + pe[9], sab = pe[10] + pe[11];
      float scd = pe[12] + pe[13], sef = pe[14] + pe[15];
      l_lane += ((s01 + s23) + (s45 + s67)) + ((s89 + sab) + (scd + sef));
    }

    // pack P -> bf16 pairs (cvt_pk), swizzled ds_write_b64 into wave-private Pt
#pragma unroll
    for (int mi = 0; mi < 4; ++mi) {
      uint2 d;
      asm("v_cvt_pk_bf16_f32 %0, %1, %2"
          : "=v"(d.x) : "v"(pe[mi * 4 + 0]), "v"(pe[mi * 4 + 1]));
      asm("v_cvt_pk_bf16_f32 %0, %1, %2"
          : "=v"(d.y) : "v"(pe[mi * 4 + 2]), "v"(pe[mi * 4 + 3]));
      const int pc = (2 * mi + (g >> 1)) ^ (c & 7);
      *(uint2*)&Pt[w][c * 64 + pc * 8 + (g & 1) * 4] = d;
    }
    asm volatile("s_waitcnt lgkmcnt(0)" ::: "memory");
    __builtin_amdgcn_sched_barrier(0);

    // PV: O[q][e] += P^T[q][kv] * V[kv][e]
#pragma unroll
    for (int ks = 0; ks < 2; ++ks) {
      const bf16x8 pa =
          *(const bf16x8*)&Pt[w][c * 64 + (((ks * 4 + g) ^ (c & 7))) * 8];
#pragma unroll
      for (int ne = 0; ne < 4; ++ne) {
        const int e = ne * 16 + c;
        const bf16x8 bv8 =
            *(const bf16x8*)&Vt[cur][e * 64 + ((ks * 4 + g) ^ (e & 7)) * 8];
        O[ne] = __builtin_amdgcn_mfma_f32_16x16x32_bf16(pa, bv8, O[ne], 0, 0, 0);
      }
    }
    __syncthreads();  // waves done reading cur; next iter's stage overwrites it
  }

  // epilogue: finish l reduction, normalize, store concat layout [B,S,H*E]
  float l = l_lane;
  l += __shfl_xor(l, 16);
  l += __shfl_xor(l, 32);
  const float invl = 1.f / l;
  const int base = (lane >> 2) & 12;  // = 4*g
  float il[4];
#pragma unroll
  for (int r = 0; r < 4; ++r) il[r] = __shfl(invl, base + r);
#pragma unroll
  for (int r = 0; r < 4; ++r) {
    const int qg = q0w + g * 4 + r;
    const size_t ro = ((size_t)(bz * S_ + qg)) * 1024 + hh * 64;
#pragma unroll
    for (int ne = 0; ne < 4; ++ne)
      att[ro + ne * 16 + c] = f2bf(O[ne][r] * il[r]);
  }
}

// ---------------------------------------------------------------------------
// Output projection: out[4096x1024] = att(bf16) @ Wo + bo, -> f32 d_out
// ---------------------------------------------------------------------------
__global__ __launch_bounds__(256, 2)
void out_gemm(const unsigned short* __restrict__ att,
              const unsigned short* __restrict__ WoT,
              const float* __restrict__ bo, float* __restrict__ outp) {
  __shared__ unsigned short At[128 * 32];
  __shared__ unsigned short Bt[128 * 32];

  const int tid = threadIdx.x;
  const int lane = tid & 63;
  const int w = tid >> 6;
  const int g = lane >> 4, c = lane & 15;
  const int wm = w >> 1, wn = w & 1;
  const int m0 = blockIdx.x * 128;
  const int n0 = blockIdx.y * 128;

  f32x4 acc[4][4];
#pragma unroll
  for (int i = 0; i < 4; ++i)
#pragma unroll
    for (int j = 0; j < 4; ++j) acc[i][j] = fzero();

  for (int kt = 0; kt < 32; ++kt) {
    const int k0 = kt * 32;
#pragma unroll
    for (int u = 0; u < 2; ++u) {
      const int row = w * 32 + u * 16 + (lane >> 2);
      const int ch = (lane & 3) ^ ((row >> 1) & 3);
      gld_lds16(att + (size_t)(m0 + row) * 1024 + k0 + ch * 8,
                &At[(w * 32 + u * 16) * 32]);
      gld_lds16(WoT + (size_t)(n0 + row) * 1024 + k0 + ch * 8,
                &Bt[(w * 32 + u * 16) * 32]);
    }
    __syncthreads();

    bf16x8 af[4], bfr[4];
#pragma unroll
    for (int mi = 0; mi < 4; ++mi) {
      const int row = wm * 64 + mi * 16 + c;
      af[mi] = *(const bf16x8*)&At[row * 32 + ((g ^ ((row >> 1) & 3))) * 8];
    }
#pragma unroll
    for (int ni = 0; ni < 4; ++ni) {
      const int row = wn * 64 + ni * 16 + c;
      bfr[ni] = *(const bf16x8*)&Bt[row * 32 + ((g ^ ((row >> 1) & 3))) * 8];
    }
#pragma unroll
    for (int mi = 0; mi < 4; ++mi)
#pragma unroll
      for (int ni = 0; ni < 4; ++ni)
        acc[mi][ni] = __builtin_amdgcn_mfma_f32_16x16x32_bf16(af[mi], bfr[ni],
                                                              acc[mi][ni], 0, 0, 0);
    __syncthreads();
  }

#pragma unroll
  for (int ni = 0; ni < 4; ++ni) {
    const int colb = n0 + wn * 64 + ni * 16 + c;
    const float bc = bo[colb];
#pragma unroll
    for (int mi = 0; mi < 4; ++mi)
#pragma unroll
      for (int r = 0; r < 4; ++r) {
        const int row = m0 + wm * 64 + mi * 16 + g * 4 + r;
        outp[(size_t)row * 1024 + colb] = acc[mi][ni][r] + bc;
      }
  }
}

// ---------------------------------------------------------------------------
extern "C" void kernel_launch(void* const* d_in, const int* in_sizes, int n_in,
                              void* d_out, int out_size, void* d_ws, size_t ws_size,
                              hipStream_t stream) {
  const float* Q  = (const float*)d_in[0];
  const float* T  = (const float*)d_in[1];
  const float* V  = (const float*)d_in[2];
  const float* Wq = (const float*)d_in[3];
  const float* bq = (const float*)d_in[4];
  const float* Wk = (const float*)d_in[5];
  const float* bk = (const float*)d_in[6];
  const float* Wv = (const float*)d_in[7];
  const float* bv = (const float*)d_in[8];
  const float* Wo = (const float*)d_in[9];
  const float* bo = (const float*)d_in[10];

  const size_t MB = 1024ull * 1024ull;
  if (ws_size < 40 * MB) return;  // need 40 MB scratch; clean fail otherwise

  uint8_t* ws = (uint8_t*)d_ws;
  unsigned short* Wt  = (unsigned short*)(ws);            // 8MB: WqT,WkT,WvT,WoT
  unsigned short* qb  = (unsigned short*)(ws + 8 * MB);   // 8MB  [B,H,S,E]
  unsigned short* kb  = (unsigned short*)(ws + 16 * MB);  // 8MB  [B,H,S,E]
  unsigned short* vtb = (unsigned short*)(ws + 24 * MB);  // 8MB  [B,H,E,S]
  unsigned short* attb = (unsigned short*)(ws + 32 * MB); // 8MB  [B,S,H*E]

  prep_weights<<<dim3(512, 1, 4), 256, 0, stream>>>(Wq, Wk, Wv, Wo, Wt);
  proj_gemm<<<dim3(32, 24), 256, 0, stream>>>(Q, T, V, Wt, bq, bk, bv, qb, kb, vtb);
  attn_kernel<<<dim3(1024), 256, 0, stream>>>(qb, kb, vtb, attb);
  out_gemm<<<dim3(32, 8), 256, 0, stream>>>(attb, Wt + 3ull * 1024ull * 1024ull,
                                            bo, (float*)d_out);
}